// Round 15
// baseline (52.227 us; speedup 1.0000x reference)
//
#include <hip/hip_runtime.h>
#include <hip/hip_bf16.h>
#include <math.h>

typedef __attribute__((ext_vector_type(8))) short bf16x8;
typedef __attribute__((ext_vector_type(4))) float f32x4;

#define T_TOT 16384
#define E_ 256
#define FF_ 1024
#define NQ 10
#define TOKS 256                // tokens per block
#define NSUB 4                  // subtiles of 64 tokens
#define CH 64                   // f per chunk
#define NCH (FF_ / CH)          // 16 chunks per subtile
#define HG (64 * CH)            // shorts per hs buffer (4096 = 8 KiB)

// paired f32->bf16 RNE via v_cvt_pk_bf16_f32
__device__ __forceinline__ unsigned pkbf(float a, float b) {
    __hip_bfloat162 t = __float22bfloat162_rn(make_float2(a, b));
    return *(unsigned*)&t;
}

// ---------------------------------------------------------------------------
// Prep (coalesced): bf16 MFMA B-fragments for w2 and w1^T.  (unchanged)
// ---------------------------------------------------------------------------
__global__ __launch_bounds__(256) void ffq_prep(
    const float* __restrict__ w2, const float* __restrict__ w1,
    uint4* __restrict__ w2f, uint4* __restrict__ w1f)
{
    int id = blockIdx.x * 256 + threadIdx.x;
    if (id < 32768) {
        int n  = id >> 7;
        int k0 = (id & 127) * 8;
        const float4* s = (const float4*)(w2 + (size_t)n * FF_ + k0);
        float4 a = s[0], b = s[1];
        uint4 v;
        v.x = pkbf(a.x, a.y);
        v.y = pkbf(a.z, a.w);
        v.z = pkbf(b.x, b.y);
        v.w = pkbf(b.z, b.w);
        int idx = ((k0 >> 5) * 16 + (n >> 4)) * 64 + ((k0 >> 3) & 3) * 16 + (n & 15);
        w2f[idx] = v;
    } else if (id < 32768 + 4096) {
        int id2 = id - 32768;
        int l = id2 & 63, nt = id2 >> 6;
        int n = nt * 16 + (l & 15);
        int g = l >> 4;
        float o[8];
#pragma unroll
        for (int j = 0; j < 8; ++j) {
            int k = g * 8 + j;
            o[j] = (k < NQ) ? w1[n * NQ + k] : 0.f;
        }
        uint4 v;
        v.x = pkbf(o[0], o[1]);
        v.y = pkbf(o[2], o[3]);
        v.z = pkbf(o[4], o[5]);
        v.w = pkbf(o[6], o[7]);
        w1f[id2] = v;
    }
}

// ---------------------------------------------------------------------------
// Fused kernel v15 (B persistent in LDS):
//  - grid 256 = 64 token-groups x 4 col-groups. Block: 256 tok x 64 cols,
//    512 thr = 8 waves (tp 0/1 token-halves x wc 0..3 col-tiles).
//  - Prologue: block's w2f slice (32kk x 4 col-tiles = 128 KiB) copied into
//    LDS ONCE (coalesced dwordx4). Hot loop has ZERO global B loads:
//    A and B both ds_read_b128.
//  - Per subtile (64 tok): q phase-0, then 16 chunks (CH=64): h-phase into
//    dbuf'd hs (verified R13 granule layout, bias-in-C), out-phase 4 MFMA.
//  - LDS 148 KiB -> 1 block/CU.
// ---------------------------------------------------------------------------
__global__ __launch_bounds__(512, 2) void ffq_mfma(
    const float* __restrict__ x, const float* __restrict__ theta,
    const float* __restrict__ b1, const float* __restrict__ b2,
    const bf16x8* __restrict__ w1f, const bf16x8* __restrict__ w2f,
    float* __restrict__ out)
{
    __shared__ bf16x8        Bl[8192];          // 128 KiB persistent B
    __shared__ unsigned short q_s[4 * 64 * 8];  // 4 KiB
    __shared__ unsigned short hs[2 * HG];       // 16 KiB (double buffer)

    const int tid = threadIdx.x;
    const int l   = tid & 63;
    const int wv  = tid >> 6;        // 0..7
    const int lr  = l & 15;
    const int g   = l >> 4;          // 0..3
    const int tp  = wv >> 2;         // token half 0/1
    const int wc  = wv & 3;          // col-tile 0..3
    const int cb  = blockIdx.x & 3;  // col group
    const int tb  = (blockIdx.x >> 2) * TOKS;

    // ---- Prologue: stage the block's B slice into LDS (once) ----
#pragma unroll
    for (int half = 0; half < 2; ++half) {
        bf16x8 tmp[8];
#pragma unroll
        for (int i = 0; i < 8; ++i) {
            int e  = (half * 8 + i) * 512 + tid;
            int kk = e >> 8, wcl = (e >> 6) & 3, ll = e & 63;
            tmp[i] = w2f[(kk * 16 + cb * 4 + wcl) * 64 + ll];
        }
#pragma unroll
        for (int i = 0; i < 8; ++i) {
            int e = (half * 8 + i) * 512 + tid;
            Bl[e] = tmp[i];
        }
    }
    // (first __syncthreads below covers completion before any B use)

    const int col  = (cb * 4 + wc) * 16 + lr;
    const float bbv = b2[col];

    for (int s = 0; s < NSUB; ++s) {
        // ---- q phase: threads 0..63 for this subtile's 64 tokens ----
        if (tid < 64) {
            const int t = tb + s * 64 + tid;
            float xv[NQ];
            {
                float4 a = *(const float4*)(x + (size_t)t * E_);
                float4 b = *(const float4*)(x + (size_t)t * E_ + 4);
                float2 c = *(const float2*)(x + (size_t)t * E_ + 8);
                xv[0]=a.x; xv[1]=a.y; xv[2]=a.z; xv[3]=a.w;
                xv[4]=b.x; xv[5]=b.y; xv[6]=b.z; xv[7]=b.w;
                xv[8]=c.x; xv[9]=c.y;
            }
            float mm[NQ];
#pragma unroll
            for (int w = 0; w < NQ; ++w) mm[w] = cosf(theta[w]) * cosf(xv[w]);
            float qv[NQ];
            {
                float p = mm[0];
#pragma unroll
                for (int w = 1; w < NQ; ++w) { p *= mm[w]; qv[w] = p; }
                float p0 = mm[1];
#pragma unroll
                for (int w = 2; w < NQ; ++w) p0 *= mm[w];
                qv[0] = p0;
            }
            uint4 s0, s1;
            s0.x = pkbf(qv[0], qv[1]);
            s0.y = pkbf(qv[2], qv[3]);
            s0.z = pkbf(qv[4], qv[5]);
            s0.w = pkbf(qv[6], qv[7]);
            s1.x = pkbf(qv[8], qv[9]);
            s1.y = 0; s1.z = 0; s1.w = 0;
            int tt = tid >> 4, r = tid & 15;
            uint4* base = (uint4*)q_s + tt * 64;
            base[r]      = s0;
            base[16 + r] = s1;
            base[32 + r] = make_uint4(0, 0, 0, 0);
            base[48 + r] = make_uint4(0, 0, 0, 0);
        }
        __syncthreads();

        // wave's q fragments for its two token-tiles (fixed per subtile)
        bf16x8 qfr[2];
        qfr[0] = ((const bf16x8*)q_s)[(tp * 2 + 0) * 64 + l];
        qfr[1] = ((const bf16x8*)q_s)[(tp * 2 + 1) * 64 + l];

        f32x4 acc[2];
        acc[0] = (f32x4){0.f, 0.f, 0.f, 0.f};
        acc[1] = (f32x4){0.f, 0.f, 0.f, 0.f};

        // ---- h-phase: wave (tp,wc) computes f-tile c*4+wc for tt=tp*2+{0,1}
#define H_PHASE(cc, hdst)                                                      \
        {                                                                      \
            const int ntg = (cc) * 4 + wc;                                     \
            bf16x8 wf  = w1f[ntg * 64 + l];                                    \
            f32x4  bbc = *(const f32x4*)(b1 + ntg * 16 + g * 4);               \
            const int fl  = wc * 16 + g * 4;      /* f local in 64-chunk */    \
            const int kkl = fl >> 5;                                           \
            const int sl  = (fl & 31) >> 3;                                    \
            const int sub = (fl & 7) * 2;                                      \
            _Pragma("unroll")                                                  \
            for (int j = 0; j < 2; ++j) {                                      \
                const int tt = tp * 2 + j;                                     \
                f32x4 d = __builtin_amdgcn_mfma_f32_16x16x32_bf16(             \
                        wf, qfr[j], bbc, 0, 0, 0);                             \
                unsigned p0 = pkbf(fmaxf(d[0], 0.f), fmaxf(d[1], 0.f));        \
                unsigned p1 = pkbf(fmaxf(d[2], 0.f), fmaxf(d[3], 0.f));        \
                unsigned byteoff = (unsigned)((tt * 2 + kkl) * 64 + lr         \
                                   + 16 * sl) * 16u + (unsigned)sub;           \
                *(uint2*)((char*)(hdst) + byteoff) = make_uint2(p0, p1);       \
            }                                                                  \
        }

        H_PHASE(0, hs)
        __syncthreads();

        for (int c = 0; c < NCH; ++c) {
            const bf16x8*   hc = (const bf16x8*)(hs + (c & 1) * HG);
            unsigned short* hn = hs + ((c & 1) ^ 1) * HG;

            // ---- out-phase: 2 kk steps, A+B from LDS only ----
            __builtin_amdgcn_s_setprio(1);
#pragma unroll
            for (int kkl = 0; kkl < 2; ++kkl) {
                const int kk = c * 2 + kkl;
                bf16x8 bb  = Bl[(kk * 4 + wc) * 64 + l];
                bf16x8 af0 = hc[((tp * 2 + 0) * 2 + kkl) * 64 + l];
                bf16x8 af1 = hc[((tp * 2 + 1) * 2 + kkl) * 64 + l];
                acc[0] = __builtin_amdgcn_mfma_f32_16x16x32_bf16(
                    af0, bb, acc[0], 0, 0, 0);
                acc[1] = __builtin_amdgcn_mfma_f32_16x16x32_bf16(
                    af1, bb, acc[1], 0, 0, 0);
            }
            __builtin_amdgcn_s_setprio(0);

            if (c < NCH - 1) {
                H_PHASE(c + 1, hn)
            }
            __syncthreads();
        }
#undef H_PHASE

        // ---- epilogue for this subtile: + b2, store fp32 ----
#pragma unroll
        for (int j = 0; j < 2; ++j) {
            const int tt = tp * 2 + j;
#pragma unroll
            for (int r = 0; r < 4; ++r) {
                int tr = tb + s * 64 + tt * 16 + g * 4 + r;
                out[(size_t)tr * E_ + col] = acc[j][r] + bbv;
            }
        }
    }
}

extern "C" void kernel_launch(void* const* d_in, const int* in_sizes, int n_in,
                              void* d_out, int out_size, void* d_ws, size_t ws_size,
                              hipStream_t stream) {
    const float* x     = (const float*)d_in[0];
    const float* theta = (const float*)d_in[1];
    const float* w1    = (const float*)d_in[2];
    const float* b1    = (const float*)d_in[3];
    const float* w2    = (const float*)d_in[4];
    const float* b2    = (const float*)d_in[5];
    float* out = (float*)d_out;

    uint4* w2f = (uint4*)d_ws;                          // 512 KiB
    uint4* w1f = (uint4*)((char*)d_ws + 512 * 1024);    // 64 KiB

    hipLaunchKernelGGL(ffq_prep, dim3(144), dim3(256), 0, stream,
                       w2, w1, w2f, w1f);
    hipLaunchKernelGGL(ffq_mfma, dim3(T_TOT / TOKS * 4), dim3(512), 0, stream,
                       x, theta, b1, b2,
                       (const bf16x8*)w1f, (const bf16x8*)w2f, out);
}

// Round 16
// 37.885 us; speedup vs baseline: 1.3786x; 1.3786x over previous
//
#include <hip/hip_runtime.h>
#include <hip/hip_bf16.h>
#include <math.h>

typedef __attribute__((ext_vector_type(8))) short bf16x8;
typedef __attribute__((ext_vector_type(4))) float f32x4;

#define T_TOT 16384
#define E_ 256
#define FF_ 1024
#define NQ 10
#define TB 64                   // tokens per block
#define CH 128                  // f per chunk (4 kk, 8 f-tiles)
#define NCHUNK (FF_ / CH)       // 8
#define HG (TB * CH)            // shorts per hs buffer (8192 = 16 KiB)

// paired f32->bf16 RNE via v_cvt_pk_bf16_f32
__device__ __forceinline__ unsigned pkbf(float a, float b) {
    __hip_bfloat162 t = __float22bfloat162_rn(make_float2(a, b));
    return *(unsigned*)&t;
}

// ---------------------------------------------------------------------------
// Prep (coalesced): bf16 MFMA B-fragments for w2 and w1^T.  (unchanged)
// ---------------------------------------------------------------------------
__global__ __launch_bounds__(256) void ffq_prep(
    const float* __restrict__ w2, const float* __restrict__ w1,
    uint4* __restrict__ w2f, uint4* __restrict__ w1f)
{
    int id = blockIdx.x * 256 + threadIdx.x;
    if (id < 32768) {
        int n  = id >> 7;
        int k0 = (id & 127) * 8;
        const float4* s = (const float4*)(w2 + (size_t)n * FF_ + k0);
        float4 a = s[0], b = s[1];
        uint4 v;
        v.x = pkbf(a.x, a.y);
        v.y = pkbf(a.z, a.w);
        v.z = pkbf(b.x, b.y);
        v.w = pkbf(b.z, b.w);
        int idx = ((k0 >> 5) * 16 + (n >> 4)) * 64 + ((k0 >> 3) & 3) * 16 + (n & 15);
        w2f[idx] = v;
    } else if (id < 32768 + 4096) {
        int id2 = id - 32768;
        int l = id2 & 63, nt = id2 >> 6;
        int n = nt * 16 + (l & 15);
        int g = l >> 4;
        float o[8];
#pragma unroll
        for (int j = 0; j < 8; ++j) {
            int k = g * 8 + j;
            o[j] = (k < NQ) ? w1[n * NQ + k] : 0.f;
        }
        uint4 v;
        v.x = pkbf(o[0], o[1]);
        v.y = pkbf(o[2], o[3]);
        v.z = pkbf(o[4], o[5]);
        v.w = pkbf(o[6], o[7]);
        w1f[id2] = v;
    }
}

// ---------------------------------------------------------------------------
// Fused kernel v16 (LDS-traffic-halved, acc[2][4]):
//  - grid 512 = 256 token-groups x 2 col-halves; block 256 thr = 4 waves
//    (wm token-half x wn col-half). Wave tile: 32 tok x 64 cols, acc[2][4]
//    -> each A ds_read feeds 4 MFMAs (was 2 in all prior rounds).
//  - B from global w2f (bf16 granules, depth-1 prefetch, shared via L1).
//  - CH=128, hs double-buffered (32 KiB) + q 4 KiB = 36 KiB; 2 blocks/CU.
//  - Per-CU LDS traffic ~0.77 MB (vs 1.8 MB in R10) -> predicted ~2x faster.
// ---------------------------------------------------------------------------
__global__ __launch_bounds__(256, 2) void ffq_mfma(
    const float* __restrict__ x, const float* __restrict__ theta,
    const float* __restrict__ b1, const float* __restrict__ b2,
    const bf16x8* __restrict__ w1f, const bf16x8* __restrict__ w2f,
    float* __restrict__ out)
{
    __shared__ unsigned short q_s[4 * 64 * 8];   // 4 KiB
    __shared__ unsigned short hs[2 * HG];        // 32 KiB (double buffer)

    const int tid = threadIdx.x;
    const int l   = tid & 63;
    const int wv  = tid >> 6;        // 0..3
    const int lr  = l & 15;
    const int g   = l >> 4;          // 0..3
    const int wm  = wv >> 1;         // token half 0/1 (32 tokens each)
    const int wn  = wv & 1;          // col half-of-block 0/1 (64 cols)
    const int chb = blockIdx.x & 1;  // block col half 0/1 (128 cols)
    const int tb  = (blockIdx.x >> 1) * TB;
    const int ncb = chb * 8 + wn * 4;            // wave's first col-tile

    // ---- Phase 0: threads 0..63 compute q, write B-frag granules ----
    if (tid < TB) {
        const int t = tb + tid;
        float xv[NQ];
        {
            float4 a = *(const float4*)(x + (size_t)t * E_);
            float4 b = *(const float4*)(x + (size_t)t * E_ + 4);
            float2 c = *(const float2*)(x + (size_t)t * E_ + 8);
            xv[0]=a.x; xv[1]=a.y; xv[2]=a.z; xv[3]=a.w;
            xv[4]=b.x; xv[5]=b.y; xv[6]=b.z; xv[7]=b.w;
            xv[8]=c.x; xv[9]=c.y;
        }
        float mm[NQ];
#pragma unroll
        for (int w = 0; w < NQ; ++w) mm[w] = cosf(theta[w]) * cosf(xv[w]);
        float qv[NQ];
        {
            float p = mm[0];
#pragma unroll
            for (int w = 1; w < NQ; ++w) { p *= mm[w]; qv[w] = p; }
            float p0 = mm[1];
#pragma unroll
            for (int w = 2; w < NQ; ++w) p0 *= mm[w];
            qv[0] = p0;
        }
        uint4 s0, s1;
        s0.x = pkbf(qv[0], qv[1]);
        s0.y = pkbf(qv[2], qv[3]);
        s0.z = pkbf(qv[4], qv[5]);
        s0.w = pkbf(qv[6], qv[7]);
        s1.x = pkbf(qv[8], qv[9]);
        s1.y = 0; s1.z = 0; s1.w = 0;
        int tt = tid >> 4, r = tid & 15;
        uint4* base = (uint4*)q_s + tt * 64;
        base[r]      = s0;
        base[16 + r] = s1;
        base[32 + r] = make_uint4(0, 0, 0, 0);
        base[48 + r] = make_uint4(0, 0, 0, 0);
    }
    __syncthreads();

    // persistent q fragments (read once)
    bf16x8 qf[4];
#pragma unroll
    for (int tt = 0; tt < 4; ++tt) qf[tt] = ((const bf16x8*)q_s)[tt * 64 + l];

    f32x4 acc[2][4];
#pragma unroll
    for (int j = 0; j < 2; ++j)
#pragma unroll
        for (int nn = 0; nn < 4; ++nn) acc[j][nn] = (f32x4){0.f,0.f,0.f,0.f};

    // ---- h-phase: wave wv does f-tiles wv*2, wv*2+1 of chunk cc, tt=0..3 ----
#define H_PHASE(cc, hdst)                                                      \
    {                                                                          \
        _Pragma("unroll")                                                      \
        for (int fi = 0; fi < 2; ++fi) {                                       \
            const int ftl = wv * 2 + fi;          /* 0..7 */                   \
            const int ntg = (cc) * 8 + ftl;                                    \
            bf16x8 wf  = w1f[ntg * 64 + l];                                    \
            f32x4  bbc = *(const f32x4*)(b1 + ntg * 16 + g * 4);               \
            const int fl  = ftl * 16 + g * 4;     /* 0..127 */                 \
            const int kkl = fl >> 5;              /* 0..3 */                   \
            const int sl  = (fl & 31) >> 3;                                    \
            const int sub = (fl & 7) * 2;                                      \
            _Pragma("unroll")                                                  \
            for (int tt = 0; tt < 4; ++tt) {                                   \
                f32x4 d = __builtin_amdgcn_mfma_f32_16x16x32_bf16(             \
                        wf, qf[tt], bbc, 0, 0, 0);                             \
                unsigned p0 = pkbf(fmaxf(d[0], 0.f), fmaxf(d[1], 0.f));        \
                unsigned p1 = pkbf(fmaxf(d[2], 0.f), fmaxf(d[3], 0.f));        \
                unsigned byteoff = (unsigned)((tt * 4 + kkl) * 64 + lr         \
                                   + 16 * sl) * 16u + (unsigned)sub;           \
                *(uint2*)((char*)(hdst) + byteoff) = make_uint2(p0, p1);       \
            }                                                                  \
        }                                                                      \
    }

    // ---- one out-step (kk-local J in chunk c): 2 A-reads, 4 B, 8 MFMA ----
#define OUT_STEP(J)                                                            \
    {                                                                          \
        const int kk  = c * 4 + (J);                                           \
        const int kkn = (kk + 1 < 32) ? kk + 1 : 31;                           \
        bf16x8 bn0 = w2f[(kkn * 16 + ncb + 0) * 64 + l];                       \
        bf16x8 bn1 = w2f[(kkn * 16 + ncb + 1) * 64 + l];                       \
        bf16x8 bn2 = w2f[(kkn * 16 + ncb + 2) * 64 + l];                       \
        bf16x8 bn3 = w2f[(kkn * 16 + ncb + 3) * 64 + l];                       \
        bf16x8 af0 = hc[((wm * 2 + 0) * 4 + (J)) * 64 + l];                    \
        bf16x8 af1 = hc[((wm * 2 + 1) * 4 + (J)) * 64 + l];                    \
        acc[0][0] = __builtin_amdgcn_mfma_f32_16x16x32_bf16(af0, bc0, acc[0][0], 0, 0, 0); \
        acc[1][0] = __builtin_amdgcn_mfma_f32_16x16x32_bf16(af1, bc0, acc[1][0], 0, 0, 0); \
        acc[0][1] = __builtin_amdgcn_mfma_f32_16x16x32_bf16(af0, bc1, acc[0][1], 0, 0, 0); \
        acc[1][1] = __builtin_amdgcn_mfma_f32_16x16x32_bf16(af1, bc1, acc[1][1], 0, 0, 0); \
        acc[0][2] = __builtin_amdgcn_mfma_f32_16x16x32_bf16(af0, bc2, acc[0][2], 0, 0, 0); \
        acc[1][2] = __builtin_amdgcn_mfma_f32_16x16x32_bf16(af1, bc2, acc[1][2], 0, 0, 0); \
        acc[0][3] = __builtin_amdgcn_mfma_f32_16x16x32_bf16(af0, bc3, acc[0][3], 0, 0, 0); \
        acc[1][3] = __builtin_amdgcn_mfma_f32_16x16x32_bf16(af1, bc3, acc[1][3], 0, 0, 0); \
        bc0 = bn0; bc1 = bn1; bc2 = bn2; bc3 = bn3;                            \
    }

    // ---- prologue: chunk 0 h-phase into buf0; init B prefetch ----
    H_PHASE(0, hs)
    bf16x8 bc0 = w2f[(0 * 16 + ncb + 0) * 64 + l];
    bf16x8 bc1 = w2f[(0 * 16 + ncb + 1) * 64 + l];
    bf16x8 bc2 = w2f[(0 * 16 + ncb + 2) * 64 + l];
    bf16x8 bc3 = w2f[(0 * 16 + ncb + 3) * 64 + l];
    __syncthreads();

    for (int c = 0; c < NCHUNK; ++c) {
        const bf16x8*   hc = (const bf16x8*)(hs + (c & 1) * HG);
        unsigned short* hn = hs + ((c & 1) ^ 1) * HG;

        __builtin_amdgcn_s_setprio(1);
        OUT_STEP(0)
        OUT_STEP(1)
        OUT_STEP(2)
        OUT_STEP(3)
        __builtin_amdgcn_s_setprio(0);

        if (c < NCHUNK - 1) {
            H_PHASE(c + 1, hn)
        }
        __syncthreads();
    }
#undef OUT_STEP
#undef H_PHASE

    // ---- epilogue: + b2, store fp32 ----
#pragma unroll
    for (int nn = 0; nn < 4; ++nn) {
        const int col = (ncb + nn) * 16 + lr;
        const float bbv = b2[col];
#pragma unroll
        for (int j = 0; j < 2; ++j) {
#pragma unroll
            for (int r = 0; r < 4; ++r) {
                int tr = tb + (wm * 2 + j) * 16 + g * 4 + r;
                out[(size_t)tr * E_ + col] = acc[j][nn][r] + bbv;
            }
        }
    }
}

extern "C" void kernel_launch(void* const* d_in, const int* in_sizes, int n_in,
                              void* d_out, int out_size, void* d_ws, size_t ws_size,
                              hipStream_t stream) {
    const float* x     = (const float*)d_in[0];
    const float* theta = (const float*)d_in[1];
    const float* w1    = (const float*)d_in[2];
    const float* b1    = (const float*)d_in[3];
    const float* w2    = (const float*)d_in[4];
    const float* b2    = (const float*)d_in[5];
    float* out = (float*)d_out;

    uint4* w2f = (uint4*)d_ws;                          // 512 KiB
    uint4* w1f = (uint4*)((char*)d_ws + 512 * 1024);    // 64 KiB

    hipLaunchKernelGGL(ffq_prep, dim3(144), dim3(256), 0, stream,
                       w2, w1, w2f, w1f);
    hipLaunchKernelGGL(ffq_mfma, dim3(2 * T_TOT / TB), dim3(256), 0, stream,
                       x, theta, b1, b2,
                       (const bf16x8*)w1f, (const bf16x8*)w2f, out);
}